// Round 3
// baseline (94.553 us; speedup 1.0000x reference)
//
#include <hip/hip_runtime.h>
#include <hip/hip_bf16.h>

#define N_ROWS 8192
#define K_CENT 128
#define D_DIM  512

typedef short v8s __attribute__((ext_vector_type(8)));
typedef float v4f __attribute__((ext_vector_type(4)));

// fp32 -> bf16 round-to-nearest-even (bit trick; inputs are finite normals)
__device__ inline unsigned short f2bf(float f) {
    union { float f; unsigned u; } v; v.f = f;
    unsigned r = v.u + 0x7FFFu + ((v.u >> 16) & 1u);
    return (unsigned short)(r >> 16);
}

// Fully fused single kernel: block = 4 waves, one 16-row x-tile per block.
// Wave w handles centroid groups {2w, 2w+1}. No workspace, no prep pass:
// centroids are read fp32 (L2-resident, 256 KiB), converted in-register,
// and ||c||^2 is accumulated in-loop and shuffle-reduced, exploiting that
// lanes {n16, n16+16, n16+32, n16+48} read the SAME c-row at disjoint
// quad k-slots (k = quad*8 + i*32 .. +7 covers all 512 dims over i=0..15).
// D-frag layout (gfx950 16x16x32): D[m = quad*4 + reg][n = lane&15].
__global__ __launch_bounds__(256) void dist_fused(const float* __restrict__ x,
                                                  const float* __restrict__ c,
                                                  float* __restrict__ out) {
    const int lane = threadIdx.x & 63;
    const int wave = threadIdx.x >> 6;
    const int n16  = lane & 15;
    const int quad = lane >> 4;
    const int rowbase = blockIdx.x * 16;
    const int g0 = wave * 2;

    // ---- Phase 1: A-frag preload + fused ||x||^2 ----
    const float* xptr = x + (size_t)(rowbase + n16) * D_DIM + quad * 8;
    v8s afrag[16];
    float sn = 0.f;
    #pragma unroll
    for (int i = 0; i < 16; ++i) {
        float4 a0 = *(const float4*)(xptr + i * 32);
        float4 a1 = *(const float4*)(xptr + i * 32 + 4);
        sn += a0.x*a0.x + a0.y*a0.y + a0.z*a0.z + a0.w*a0.w
            + a1.x*a1.x + a1.y*a1.y + a1.z*a1.z + a1.w*a1.w;
        v8s f;
        f[0] = (short)f2bf(a0.x); f[1] = (short)f2bf(a0.y);
        f[2] = (short)f2bf(a0.z); f[3] = (short)f2bf(a0.w);
        f[4] = (short)f2bf(a1.x); f[5] = (short)f2bf(a1.y);
        f[6] = (short)f2bf(a1.z); f[7] = (short)f2bf(a1.w);
        afrag[i] = f;
    }

    // ---- Phase 2: fp32 c-load + convert + MFMA, fused ||c||^2 ----
    const float* c0 = c + (size_t)(g0 * 16 + n16) * D_DIM + quad * 8;
    const float* c1 = c0 + (size_t)16 * D_DIM;

    v4f acc0 = (v4f){0.f, 0.f, 0.f, 0.f};
    v4f acc1 = (v4f){0.f, 0.f, 0.f, 0.f};
    float sc0 = 0.f, sc1 = 0.f;
    #pragma unroll
    for (int i = 0; i < 16; ++i) {
        float4 p0 = *(const float4*)(c0 + i * 32);
        float4 p1 = *(const float4*)(c0 + i * 32 + 4);
        float4 q0 = *(const float4*)(c1 + i * 32);
        float4 q1 = *(const float4*)(c1 + i * 32 + 4);
        sc0 += p0.x*p0.x + p0.y*p0.y + p0.z*p0.z + p0.w*p0.w
             + p1.x*p1.x + p1.y*p1.y + p1.z*p1.z + p1.w*p1.w;
        sc1 += q0.x*q0.x + q0.y*q0.y + q0.z*q0.z + q0.w*q0.w
             + q1.x*q1.x + q1.y*q1.y + q1.z*q1.z + q1.w*q1.w;
        v8s bf0, bf1;
        bf0[0] = (short)f2bf(p0.x); bf0[1] = (short)f2bf(p0.y);
        bf0[2] = (short)f2bf(p0.z); bf0[3] = (short)f2bf(p0.w);
        bf0[4] = (short)f2bf(p1.x); bf0[5] = (short)f2bf(p1.y);
        bf0[6] = (short)f2bf(p1.z); bf0[7] = (short)f2bf(p1.w);
        bf1[0] = (short)f2bf(q0.x); bf1[1] = (short)f2bf(q0.y);
        bf1[2] = (short)f2bf(q0.z); bf1[3] = (short)f2bf(q0.w);
        bf1[4] = (short)f2bf(q1.x); bf1[5] = (short)f2bf(q1.y);
        bf1[6] = (short)f2bf(q1.z); bf1[7] = (short)f2bf(q1.w);
        acc0 = __builtin_amdgcn_mfma_f32_16x16x32_bf16(afrag[i], bf0, acc0, 0, 0, 0);
        acc1 = __builtin_amdgcn_mfma_f32_16x16x32_bf16(afrag[i], bf1, acc1, 0, 0, 0);
    }

    // ---- Reductions across the 4 quad-lanes of each row ----
    sn  += __shfl_xor(sn, 16, 64);  sn  += __shfl_xor(sn, 32, 64);
    sc0 += __shfl_xor(sc0, 16, 64); sc0 += __shfl_xor(sc0, 32, 64);
    sc1 += __shfl_xor(sc1, 16, 64); sc1 += __shfl_xor(sc1, 32, 64);
    // every lane now holds: sn = ||x_{rowbase+n16}||^2, sc{0,1} = ||c_{g*16+n16}||^2
    float xn[4];
    #pragma unroll
    for (int r = 0; r < 4; ++r) xn[r] = __shfl(sn, quad * 4 + r, 64);

    // ---- Epilogue ----
    #pragma unroll
    for (int gi = 0; gi < 2; ++gi) {
        int g = g0 + gi;
        float cn = gi ? sc1 : sc0;
        v4f acc = gi ? acc1 : acc0;
        #pragma unroll
        for (int r = 0; r < 4; ++r) {
            float d2 = xn[r] + cn - 2.0f * acc[r];
            d2 = d2 > 0.f ? d2 : 0.f;
            out[(size_t)(rowbase + quad * 4 + r) * K_CENT + g * 16 + n16] = sqrtf(d2);
        }
    }
}

extern "C" void kernel_launch(void* const* d_in, const int* in_sizes, int n_in,
                              void* d_out, int out_size, void* d_ws, size_t ws_size,
                              hipStream_t stream) {
    const float* x = (const float*)d_in[0];
    const float* c = (const float*)d_in[1];
    float* out = (float*)d_out;
    (void)d_ws; (void)ws_size;

    dist_fused<<<N_ROWS / 16, 256, 0, stream>>>(x, c, out);
}

// Round 4
// 82.614 us; speedup vs baseline: 1.1445x; 1.1445x over previous
//
#include <hip/hip_runtime.h>
#include <hip/hip_bf16.h>

#define N_ROWS 8192
#define K_CENT 128
#define D_DIM  512

typedef short v8s __attribute__((ext_vector_type(8)));
typedef float v4f __attribute__((ext_vector_type(4)));

// fp32 -> bf16 round-to-nearest-even (bit trick; inputs are finite normals)
__device__ inline unsigned short f2bf(float f) {
    union { float f; unsigned u; } v; v.f = f;
    unsigned r = v.u + 0x7FFFu + ((v.u >> 16) & 1u);
    return (unsigned short)(r >> 16);
}

// One wave per row (8192 x-rows then 128 c-rows): bf16 convert + exact fp32 norm.
__global__ __launch_bounds__(256) void prep_all(const float* __restrict__ x,
                                                const float* __restrict__ c,
                                                unsigned short* __restrict__ xb,
                                                unsigned short* __restrict__ cb,
                                                float* __restrict__ xnorm,
                                                float* __restrict__ cnorm) {
    int wave = (int)((blockIdx.x * blockDim.x + threadIdx.x) >> 6);
    int lane = threadIdx.x & 63;
    if (wave >= N_ROWS + K_CENT) return;

    const float* src;
    unsigned short* dst;
    float* nrm;
    if (wave < N_ROWS) {
        src = x + (size_t)wave * D_DIM;
        dst = xb + (size_t)wave * D_DIM;
        nrm = xnorm + wave;
    } else {
        int r = wave - N_ROWS;
        src = c + (size_t)r * D_DIM;
        dst = cb + (size_t)r * D_DIM;
        nrm = cnorm + r;
    }

    float4 a = ((const float4*)src)[lane];        // dims 4*lane   .. +3
    float4 b = ((const float4*)src)[64 + lane];   // dims 256+4*lane
    float s = a.x*a.x + a.y*a.y + a.z*a.z + a.w*a.w
            + b.x*b.x + b.y*b.y + b.z*b.z + b.w*b.w;
    #pragma unroll
    for (int off = 32; off >= 1; off >>= 1) s += __shfl_xor(s, off, 64);
    if (lane == 0) *nrm = s;

    ushort4 p0, p1;
    p0.x = f2bf(a.x); p0.y = f2bf(a.y); p0.z = f2bf(a.z); p0.w = f2bf(a.w);
    p1.x = f2bf(b.x); p1.y = f2bf(b.y); p1.z = f2bf(b.z); p1.w = f2bf(b.w);
    ((ushort4*)dst)[lane]      = p0;
    ((ushort4*)dst)[64 + lane] = p1;
}

// Pure load+MFMA kernel. Block = 4 waves; block (tile,half) covers 16 x-rows ×
// 64 centroids; wave w handles group g = half*4 + w (16 centroids).
// A-frag: xb[m = rowbase + (lane&15)][k = quad*8 + i*32 ..+7] — one v8s load.
// B-frag: cb[n = g*16 + (lane&15)][same k]                    — one v8s load.
// D-frag (gfx950 16x16x32): D[m = quad*4 + reg][n = lane&15].
// 1024 blocks × 4 waves = 16 waves/CU launched; launch_bounds(256,3) keeps
// VGPR <= ~168 so 3 blocks/CU stay resident.
__global__ __launch_bounds__(256, 3) void dist_kernel(const unsigned short* __restrict__ xb,
                                                      const unsigned short* __restrict__ cb,
                                                      const float* __restrict__ xnorm,
                                                      const float* __restrict__ cnorm,
                                                      float* __restrict__ out) {
    const int lane = threadIdx.x & 63;
    const int wave = threadIdx.x >> 6;
    const int n16  = lane & 15;
    const int quad = lane >> 4;

    const int tile = blockIdx.x >> 1;          // 0..511: which 16-row x tile
    const int half = blockIdx.x & 1;           // 0/1: which 64-centroid half
    const int rowbase = tile * 16;
    const int g = half * 4 + wave;             // centroid group 0..7

    const unsigned short* aptr = xb + (size_t)(rowbase + n16) * D_DIM + quad * 8;
    const unsigned short* bptr = cb + (size_t)(g * 16 + n16) * D_DIM + quad * 8;

    v4f acc = (v4f){0.f, 0.f, 0.f, 0.f};
    #pragma unroll
    for (int i = 0; i < 16; ++i) {
        v8s af = *(const v8s*)(aptr + i * 32);
        v8s bf = *(const v8s*)(bptr + i * 32);
        acc = __builtin_amdgcn_mfma_f32_16x16x32_bf16(af, bf, acc, 0, 0, 0);
    }

    const float cn = cnorm[g * 16 + n16];
    #pragma unroll
    for (int r = 0; r < 4; ++r) {
        int row = rowbase + quad * 4 + r;
        float d2 = xnorm[row] + cn - 2.0f * acc[r];
        d2 = d2 > 0.f ? d2 : 0.f;
        out[(size_t)row * K_CENT + g * 16 + n16] = sqrtf(d2);
    }
}

// Correctness fallback if ws is unexpectedly tiny: one thread per output.
__global__ void naive_kernel(const float* __restrict__ x, const float* __restrict__ c,
                             float* __restrict__ out) {
    int idx = blockIdx.x * blockDim.x + threadIdx.x;
    if (idx >= N_ROWS * K_CENT) return;
    int n = idx / K_CENT, k = idx % K_CENT;
    const float* xr = x + (size_t)n * D_DIM;
    const float* cr = c + (size_t)k * D_DIM;
    float s = 0.f;
    for (int d = 0; d < D_DIM; ++d) { float df = xr[d] - cr[d]; s += df * df; }
    out[idx] = sqrtf(s);
}

extern "C" void kernel_launch(void* const* d_in, const int* in_sizes, int n_in,
                              void* d_out, int out_size, void* d_ws, size_t ws_size,
                              hipStream_t stream) {
    const float* x = (const float*)d_in[0];
    const float* c = (const float*)d_in[1];
    float* out = (float*)d_out;

    // ws layout: xb (8 MiB) | cb (128 KiB) | xnorm (32 KiB) | cnorm (512 B)
    const size_t xb_off = 0;
    const size_t cb_off = (size_t)N_ROWS * D_DIM * sizeof(unsigned short);
    const size_t xn_off = cb_off + (size_t)K_CENT * D_DIM * sizeof(unsigned short);
    const size_t cn_off = xn_off + (size_t)N_ROWS * sizeof(float);
    const size_t need   = cn_off + (size_t)K_CENT * sizeof(float);

    if (ws_size < need) {
        int total = N_ROWS * K_CENT;
        naive_kernel<<<(total + 255) / 256, 256, 0, stream>>>(x, c, out);
        return;
    }

    unsigned short* xb = (unsigned short*)((char*)d_ws + xb_off);
    unsigned short* cb = (unsigned short*)((char*)d_ws + cb_off);
    float* xnorm = (float*)((char*)d_ws + xn_off);
    float* cnorm = (float*)((char*)d_ws + cn_off);

    const int total_rows = N_ROWS + K_CENT;                 // 8320 waves
    prep_all<<<(total_rows * 64 + 255) / 256, 256, 0, stream>>>(x, c, xb, cb, xnorm, cnorm);
    dist_kernel<<<(N_ROWS / 16) * 2, 256, 0, stream>>>(xb, cb, xnorm, cnorm, out);
}

// Round 5
// 74.281 us; speedup vs baseline: 1.2729x; 1.1122x over previous
//
#include <hip/hip_runtime.h>
#include <hip/hip_bf16.h>

#define N_ROWS 8192
#define K_CENT 128
#define D_DIM  512
#define LDS_PITCH 520   // ushorts per LDS row: 512 + 8 pad -> row stride 1040B = 16B-aligned,
                        // base banks (4*row)%32 -> only 2-way aliasing (free, m136)

typedef short v8s __attribute__((ext_vector_type(8)));
typedef float v4f __attribute__((ext_vector_type(4)));

// fp32 -> bf16 round-to-nearest-even (bit trick; inputs are finite normals)
__device__ inline unsigned short f2bf(float f) {
    union { float f; unsigned u; } v; v.f = f;
    unsigned r = v.u + 0x7FFFu + ((v.u >> 16) & 1u);
    return (unsigned short)(r >> 16);
}

// One wave per centroid row: exact fp32 ||c||^2 + bf16 copy. 128 waves total.
__global__ __launch_bounds__(256) void prep_centroids(const float* __restrict__ c,
                                                      float* __restrict__ cnorm,
                                                      unsigned short* __restrict__ cb) {
    int wave = (int)((blockIdx.x * blockDim.x + threadIdx.x) >> 6);
    int lane = threadIdx.x & 63;
    if (wave >= K_CENT) return;
    const float* src = c + (size_t)wave * D_DIM;
    float4 a = ((const float4*)src)[lane];
    float4 b = ((const float4*)src)[64 + lane];
    float s = a.x*a.x + a.y*a.y + a.z*a.z + a.w*a.w
            + b.x*b.x + b.y*b.y + b.z*b.z + b.w*b.w;
    #pragma unroll
    for (int off = 32; off >= 1; off >>= 1) s += __shfl_xor(s, off, 64);
    if (lane == 0) cnorm[wave] = s;
    unsigned short* dst = cb + (size_t)wave * D_DIM;
    ushort4 p0, p1;
    p0.x = f2bf(a.x); p0.y = f2bf(a.y); p0.z = f2bf(a.z); p0.w = f2bf(a.w);
    p1.x = f2bf(b.x); p1.y = f2bf(b.y); p1.z = f2bf(b.z); p1.w = f2bf(b.w);
    ((ushort4*)dst)[lane]      = p0;
    ((ushort4*)dst)[64 + lane] = p1;
}

// Block = 4 waves, stages one 16-row x-tile into LDS (bf16) once, then each
// wave runs one 16-centroid group: ds_read_b128 afrag + global v8s bfrag + MFMA.
// ||x||^2 comes from the matrix pipe: accx = mfma(af, af) -> X.X^T diagonal;
// diag[m] lives at lane 20*(m>>2)+(m&3), reg (m&3)  [D layout: col=lane&15,
// row=(lane>>4)*4+reg -- verified m89/m91].
// Grid: 1024 blocks = 4/CU exactly; launch_bounds(256,4) -> VGPR<=128, all
// 16 waves/CU resident. Half-major ordering: tile t's two halves are blocks
// t and t+512; 512%8==0 -> same XCD -> L2 reuse of the x tile.
__global__ __launch_bounds__(256, 4) void dist_kernel(const float* __restrict__ x,
                                                      const unsigned short* __restrict__ cb,
                                                      const float* __restrict__ cnorm,
                                                      float* __restrict__ out) {
    __shared__ unsigned short xlds[16 * LDS_PITCH];

    const int t    = threadIdx.x;
    const int lane = t & 63;
    const int wave = t >> 6;
    const int half = blockIdx.x >> 9;    // 0..1
    const int tile = blockIdx.x & 511;   // 0..511
    const int rowbase = tile * 16;
    const int g = half * 4 + wave;       // centroid group 0..7

    // ---- Stage x tile -> LDS (coalesced float4, f2bf, conflict-free writes) ----
    const float* xs = x + (size_t)rowbase * D_DIM;
    #pragma unroll
    for (int j = 0; j < 8; ++j) {
        int f = (j * 256 + t) * 4;               // flat float index in 16x512 tile
        float4 v = *(const float4*)(xs + f);
        int row = f >> 9;
        int k   = f & 511;
        ushort4 p;
        p.x = f2bf(v.x); p.y = f2bf(v.y); p.z = f2bf(v.z); p.w = f2bf(v.w);
        *(ushort4*)&xlds[row * LDS_PITCH + k] = p;
    }
    __syncthreads();

    // ---- MFMA loop ----
    const int n16  = lane & 15;
    const int quad = lane >> 4;
    const unsigned short* bptr = cb + (size_t)(g * 16 + n16) * D_DIM + quad * 8;
    const unsigned short* aptr = &xlds[n16 * LDS_PITCH + quad * 8];

    v4f acc  = (v4f){0.f, 0.f, 0.f, 0.f};
    v4f accx = (v4f){0.f, 0.f, 0.f, 0.f};
    #pragma unroll
    for (int i = 0; i < 16; ++i) {
        v8s af = *(const v8s*)(aptr + i * 32);
        v8s bf = *(const v8s*)(bptr + i * 32);
        acc  = __builtin_amdgcn_mfma_f32_16x16x32_bf16(af, bf, acc, 0, 0, 0);
        accx = __builtin_amdgcn_mfma_f32_16x16x32_bf16(af, af, accx, 0, 0, 0);
    }

    // ---- Epilogue: xnorm from X.X^T diagonal, cnorm exact fp32 ----
    const float cn = cnorm[g * 16 + n16];
    #pragma unroll
    for (int r = 0; r < 4; ++r) {
        float xn = __shfl(accx[r], 20 * quad + r, 64);   // diag[quad*4+r]
        int row = rowbase + quad * 4 + r;
        float d2 = xn + cn - 2.0f * acc[r];
        d2 = d2 > 0.f ? d2 : 0.f;
        out[(size_t)row * K_CENT + g * 16 + n16] = sqrtf(d2);
    }
}

// Correctness fallback if ws is unexpectedly tiny: one thread per output.
__global__ void naive_kernel(const float* __restrict__ x, const float* __restrict__ c,
                             float* __restrict__ out) {
    int idx = blockIdx.x * blockDim.x + threadIdx.x;
    if (idx >= N_ROWS * K_CENT) return;
    int n = idx / K_CENT, k = idx % K_CENT;
    const float* xr = x + (size_t)n * D_DIM;
    const float* cr = c + (size_t)k * D_DIM;
    float s = 0.f;
    for (int d = 0; d < D_DIM; ++d) { float df = xr[d] - cr[d]; s += df * df; }
    out[idx] = sqrtf(s);
}

extern "C" void kernel_launch(void* const* d_in, const int* in_sizes, int n_in,
                              void* d_out, int out_size, void* d_ws, size_t ws_size,
                              hipStream_t stream) {
    const float* x = (const float*)d_in[0];
    const float* c = (const float*)d_in[1];
    float* out = (float*)d_out;

    // ws layout: cnorm (512 B) | cb (128 KiB)
    const size_t need = 512 + (size_t)K_CENT * D_DIM * sizeof(unsigned short);
    if (ws_size < need) {
        int total = N_ROWS * K_CENT;
        naive_kernel<<<(total + 255) / 256, 256, 0, stream>>>(x, c, out);
        return;
    }

    float* cnorm = (float*)d_ws;
    unsigned short* cb = (unsigned short*)((char*)d_ws + 512);

    prep_centroids<<<(K_CENT * 64 + 255) / 256, 256, 0, stream>>>(c, cnorm, cb);
    dist_kernel<<<(N_ROWS / 16) * 2, 256, 0, stream>>>(x, cb, cnorm, out);
}

// Round 6
// 73.459 us; speedup vs baseline: 1.2872x; 1.0112x over previous
//
#include <hip/hip_runtime.h>
#include <hip/hip_bf16.h>

#define N_ROWS 8192
#define K_CENT 128
#define D_DIM  512
#define LDS_PITCH 520   // 512 + 8 pad ushorts; row stride 1040B (16B-aligned), dword
                        // stride 260 == 4 (mod 32) -> ds_read_b128 hits the bank floor

typedef short v8s __attribute__((ext_vector_type(8)));
typedef unsigned short v8u __attribute__((ext_vector_type(8)));
typedef float v4f __attribute__((ext_vector_type(4)));

// fp32 -> bf16 round-to-nearest-even (bit trick; inputs are finite normals)
__device__ inline unsigned short f2bf(float f) {
    union { float f; unsigned u; } v; v.f = f;
    unsigned r = v.u + 0x7FFFu + ((v.u >> 16) & 1u);
    return (unsigned short)(r >> 16);
}

// One wave per centroid row: exact fp32 ||c||^2 + bf16 copy. 128 waves total.
__global__ __launch_bounds__(256) void prep_centroids(const float* __restrict__ c,
                                                      float* __restrict__ cnorm,
                                                      unsigned short* __restrict__ cb) {
    int wave = (int)((blockIdx.x * blockDim.x + threadIdx.x) >> 6);
    int lane = threadIdx.x & 63;
    if (wave >= K_CENT) return;
    const float* src = c + (size_t)wave * D_DIM;
    float4 a = ((const float4*)src)[lane];
    float4 b = ((const float4*)src)[64 + lane];
    float s = a.x*a.x + a.y*a.y + a.z*a.z + a.w*a.w
            + b.x*b.x + b.y*b.y + b.z*b.z + b.w*b.w;
    #pragma unroll
    for (int off = 32; off >= 1; off >>= 1) s += __shfl_xor(s, off, 64);
    if (lane == 0) cnorm[wave] = s;
    unsigned short* dst = cb + (size_t)wave * D_DIM;
    ushort4 p0, p1;
    p0.x = f2bf(a.x); p0.y = f2bf(a.y); p0.z = f2bf(a.z); p0.w = f2bf(a.w);
    p1.x = f2bf(b.x); p1.y = f2bf(b.y); p1.z = f2bf(b.z); p1.w = f2bf(b.w);
    ((ushort4*)dst)[lane]      = p0;
    ((ushort4*)dst)[64 + lane] = p1;
}

// Block = 8 waves = 512 threads; stages ONE 16-row x-tile into LDS (bf16),
// then wave w computes centroid group g=w: ds_read_b128 afrag + global v8s
// bfrag + MFMA. ||x||^2 via matrix pipe: accx = mfma(af,af) -> X.X^T diagonal
// (D layout col=lane&15, row=quad*4+reg; diag[quad*4+r] at lane 20*quad+r).
// Grid 512 blocks = 2 blocks/CU x 8 waves = 16 waves/CU; launch_bounds(512,4)
// caps VGPR at 128 so all are resident. x is fetched from HBM exactly once.
__global__ __launch_bounds__(512, 4) void dist_kernel(const float* __restrict__ x,
                                                      const unsigned short* __restrict__ cb,
                                                      const float* __restrict__ cnorm,
                                                      float* __restrict__ out) {
    __shared__ unsigned short xlds[16 * LDS_PITCH];

    const int t    = threadIdx.x;
    const int lane = t & 63;
    const int g    = t >> 6;             // wave index == centroid group 0..7
    const int rowbase = blockIdx.x * 16;

    // ---- Stage x tile -> LDS: thread t converts floats {j*4096 + 8t .. +7} ----
    const float* xs = x + (size_t)rowbase * D_DIM;
    #pragma unroll
    for (int j = 0; j < 2; ++j) {
        int base = j * 4096 + t * 8;             // flat float index in 16x512 tile
        float4 v0 = *(const float4*)(xs + base);
        float4 v1 = *(const float4*)(xs + base + 4);
        int row = base >> 9;
        int k   = base & 511;
        v8u p;
        p[0] = f2bf(v0.x); p[1] = f2bf(v0.y); p[2] = f2bf(v0.z); p[3] = f2bf(v0.w);
        p[4] = f2bf(v1.x); p[5] = f2bf(v1.y); p[6] = f2bf(v1.z); p[7] = f2bf(v1.w);
        *(v8u*)&xlds[row * LDS_PITCH + k] = p;   // single ds_write_b128, bank-floor
    }
    __syncthreads();

    // ---- MFMA loop ----
    const int n16  = lane & 15;
    const int quad = lane >> 4;
    const unsigned short* bptr = cb + (size_t)(g * 16 + n16) * D_DIM + quad * 8;
    const unsigned short* aptr = &xlds[n16 * LDS_PITCH + quad * 8];

    v4f acc  = (v4f){0.f, 0.f, 0.f, 0.f};
    v4f accx = (v4f){0.f, 0.f, 0.f, 0.f};
    #pragma unroll
    for (int i = 0; i < 16; ++i) {
        v8s af = *(const v8s*)(aptr + i * 32);
        v8s bf = *(const v8s*)(bptr + i * 32);
        acc  = __builtin_amdgcn_mfma_f32_16x16x32_bf16(af, bf, acc, 0, 0, 0);
        accx = __builtin_amdgcn_mfma_f32_16x16x32_bf16(af, af, accx, 0, 0, 0);
    }

    // ---- Epilogue: xnorm from X.X^T diagonal, cnorm exact fp32 ----
    const float cn = cnorm[g * 16 + n16];
    #pragma unroll
    for (int r = 0; r < 4; ++r) {
        float xn = __shfl(accx[r], 20 * quad + r, 64);   // diag[quad*4+r]
        int row = rowbase + quad * 4 + r;
        float d2 = xn + cn - 2.0f * acc[r];
        d2 = d2 > 0.f ? d2 : 0.f;
        out[(size_t)row * K_CENT + g * 16 + n16] = sqrtf(d2);
    }
}

// Correctness fallback if ws is unexpectedly tiny: one thread per output.
__global__ void naive_kernel(const float* __restrict__ x, const float* __restrict__ c,
                             float* __restrict__ out) {
    int idx = blockIdx.x * blockDim.x + threadIdx.x;
    if (idx >= N_ROWS * K_CENT) return;
    int n = idx / K_CENT, k = idx % K_CENT;
    const float* xr = x + (size_t)n * D_DIM;
    const float* cr = c + (size_t)k * D_DIM;
    float s = 0.f;
    for (int d = 0; d < D_DIM; ++d) { float df = xr[d] - cr[d]; s += df * df; }
    out[idx] = sqrtf(s);
}

extern "C" void kernel_launch(void* const* d_in, const int* in_sizes, int n_in,
                              void* d_out, int out_size, void* d_ws, size_t ws_size,
                              hipStream_t stream) {
    const float* x = (const float*)d_in[0];
    const float* c = (const float*)d_in[1];
    float* out = (float*)d_out;

    // ws layout: cnorm (512 B) | cb (128 KiB)
    const size_t need = 512 + (size_t)K_CENT * D_DIM * sizeof(unsigned short);
    if (ws_size < need) {
        int total = N_ROWS * K_CENT;
        naive_kernel<<<(total + 255) / 256, 256, 0, stream>>>(x, c, out);
        return;
    }

    float* cnorm = (float*)d_ws;
    unsigned short* cb = (unsigned short*)((char*)d_ws + 512);

    prep_centroids<<<(K_CENT * 64 + 255) / 256, 256, 0, stream>>>(c, cnorm, cb);
    dist_kernel<<<N_ROWS / 16, 512, 0, stream>>>(x, cb, cnorm, out);
}